// Round 3
// baseline (135.451 us; speedup 1.0000x reference)
//
#include <hip/hip_runtime.h>
#include <math.h>

// CapsuleLayer dynamic routing, factored (u_hat never materialized):
//   s[b,m,:] = ((Sum_n e_n in[b,n,:]) / Sum_n e_n) @ W[:,m,:],  e_n = exp(logit)
//   logit[n,m] after pass p = in[b,n,:] . cum_wv[m,:],  cum_wv = Sum_{q<=p} W_m @ v_q
// (logits are LINEAR in the per-pass wv updates -> no per-n state needed at all)
// Pass 0 (uniform softmax) is just a column sum (e=1, S=2048).
//
// Grid: 1024 blocks = 64 b x 16 m-pairs -> 4 blocks/CU, 512 thr = 8 waves,
// __launch_bounds__(512,8) caps VGPR at 64 -> 32 waves/CU (100% occupancy).
// Lane l: m = m0 + (l&1), row-group rg = l>>1 (pair shares the row ->
// butterfly reduction is 17 values x 5 stages, masks {2,4,8,16,32}).
// No input LDS (inputs[b] = 128 KB, L2-resident; bx%64==b pins the 16 blocks
// of a batch to XCD b%8). W-slice (2 m, 2 KB) staged in LDS, stride 33
// (conflict-free for both tail access patterns).

#define TPB 512

__global__ __launch_bounds__(TPB, 8)
void capsule_routing_kernel(const float* __restrict__ in,
                            const float* __restrict__ W,
                            float* __restrict__ out)
{
    __shared__ float red[8 * 34];    // [wave][mi*17 + {S, xc[16]}]
    __shared__ float fin[34];
    __shared__ float cum_lds[32];    // cumulative wv[mi][d]
    __shared__ float w_lds[16 * 33 + 32];  // W[d][mi*16+c] at stride 33

    const int tid = threadIdx.x;
    const int w   = tid >> 6;
    const int l   = tid & 63;
    const int mi  = l & 1;
    const int rg  = l >> 1;
    const int b   = blockIdx.x & 63;
    const int m0  = (blockIdx.x >> 6) << 1;

    const float* __restrict__ inb = in + ((size_t)b << 15);  // b*2048*16

    // stage W[:, m0:m0+2, :] (512 floats) into LDS, stride-33 rows
    {
        int idx = tid;                 // 512 threads, one element each
        int d  = idx >> 5;             // 0..15
        int r  = idx & 31;             // mi*16 + c
        w_lds[d * 33 + r] = W[(d << 9) + (m0 << 4) + r];
    }
    __syncthreads();

    for (int pass = 0; pass < 3; ++pass) {
        float2 wv2[8];
        if (pass) {
            #pragma unroll
            for (int j = 0; j < 8; ++j) {
                wv2[j].x = cum_lds[(mi << 4) + 2 * j];
                wv2[j].y = cum_lds[(mi << 4) + 2 * j + 1];
            }
        }

        float S = 0.f;
        float2 xc[8];
        #pragma unroll
        for (int j = 0; j < 8; ++j) { xc[j].x = 0.f; xc[j].y = 0.f; }

        #pragma unroll 2
        for (int k = 0; k < 8; ++k) {
            const int r = (w << 8) + (k << 5) + rg;
            const float4* __restrict__ p = (const float4*)(inb + ((size_t)r << 4));
            float4 f0 = p[0], f1 = p[1], f2 = p[2], f3 = p[3];
            float2 iv[8];
            iv[0].x=f0.x; iv[0].y=f0.y; iv[1].x=f0.z; iv[1].y=f0.w;
            iv[2].x=f1.x; iv[2].y=f1.y; iv[3].x=f1.z; iv[3].y=f1.w;
            iv[4].x=f2.x; iv[4].y=f2.y; iv[5].x=f2.z; iv[5].y=f2.w;
            iv[6].x=f3.x; iv[6].y=f3.y; iv[7].x=f3.z; iv[7].y=f3.w;

            if (pass) {
                float2 dp; dp.x = 0.f; dp.y = 0.f;
                #pragma unroll
                for (int j = 0; j < 8; ++j) {         // float2 shape -> v_pk_fma_f32
                    dp.x += iv[j].x * wv2[j].x;
                    dp.y += iv[j].y * wv2[j].y;
                }
                const float e = __expf(dp.x + dp.y);  // |logit| small; no max-shift
                S += e;
                #pragma unroll
                for (int j = 0; j < 8; ++j) {
                    xc[j].x += e * iv[j].x;
                    xc[j].y += e * iv[j].y;
                }
            } else {                                   // uniform pass: e = 1
                #pragma unroll
                for (int j = 0; j < 8; ++j) {
                    xc[j].x += iv[j].x;
                    xc[j].y += iv[j].y;
                }
            }
        }
        if (!pass) S = 8.f;   // 8 rows per lane, e=1

        // butterfly over the 32 lanes sharing this mi
        #pragma unroll
        for (int mask = 2; mask <= 32; mask <<= 1) {
            S += __shfl_xor(S, mask);
            #pragma unroll
            for (int j = 0; j < 8; ++j) {
                xc[j].x += __shfl_xor(xc[j].x, mask);
                xc[j].y += __shfl_xor(xc[j].y, mask);
            }
        }
        if (l < 2) {          // l == mi
            float* rp = &red[w * 34 + l * 17];
            rp[0] = S;
            #pragma unroll
            for (int j = 0; j < 8; ++j) {
                rp[1 + 2 * j]     = xc[j].x;
                rp[2 + 2 * j]     = xc[j].y;
            }
        }
        __syncthreads();
        if (tid < 34) {
            float a = 0.f;
            #pragma unroll
            for (int w2 = 0; w2 < 8; ++w2) a += red[w2 * 34 + tid];
            fin[tid] = a;
        }
        __syncthreads();

        // tail on half of wave 0: s = (xc/S) @ W_m, v = squash(s)
        if (tid < 32) {
            const int tmi = tid >> 4;
            const int tc  = tid & 15;
            const float rS = 1.f / fin[tmi * 17];
            float s = 0.f;
            #pragma unroll
            for (int d = 0; d < 16; ++d)
                s += fin[tmi * 17 + 1 + d] * w_lds[d * 33 + (tmi << 4) + tc];
            s *= rS;
            float n2 = s * s;
            n2 += __shfl_xor(n2, 1);
            n2 += __shfl_xor(n2, 2);
            n2 += __shfl_xor(n2, 4);
            n2 += __shfl_xor(n2, 8);
            const float nr = sqrtf(n2);
            const float v  = s * (n2 / (1.f + n2)) / (nr + 1e-7f);
            if (pass < 2) {
                float wvv = 0.f;                      // wv[d=tc] for capsule tmi
                #pragma unroll
                for (int c2 = 0; c2 < 16; ++c2)
                    wvv += w_lds[tc * 33 + (tmi << 4) + c2] * __shfl(v, (tmi << 4) + c2);
                if (pass == 0) cum_lds[(tmi << 4) + tc] = wvv;
                else           cum_lds[(tmi << 4) + tc] += wvv;
            } else {
                out[((size_t)b << 9) + ((m0 + tmi) << 4) + tc] = v;
            }
        }
        __syncthreads();
    }
}

extern "C" void kernel_launch(void* const* d_in, const int* in_sizes, int n_in,
                              void* d_out, int out_size, void* d_ws, size_t ws_size,
                              hipStream_t stream) {
    (void)in_sizes; (void)n_in; (void)d_ws; (void)ws_size; (void)out_size;
    const float* in = (const float*)d_in[0];
    const float* W  = (const float*)d_in[1];
    float* out = (float*)d_out;
    hipLaunchKernelGGL(capsule_routing_kernel, dim3(1024), dim3(TPB), 0, stream,
                       in, W, out);
}